// Round 2
// baseline (739.451 us; speedup 1.0000x reference)
//
#include <hip/hip_runtime.h>
#include <hip/hip_bf16.h>

typedef __attribute__((ext_vector_type(8))) __bf16 bf16x8;
typedef __attribute__((ext_vector_type(4))) __bf16 bf16x4;
typedef __attribute__((ext_vector_type(4))) float f32x4;

constexpr int M = 16384;
constexpr int K = 512;
constexpr int BK = 32;

__device__ __forceinline__ void async_copy16(const void* gsrc, void* ldst) {
  __builtin_amdgcn_global_load_lds(
      (const __attribute__((address_space(1))) unsigned int*)(gsrc),
      (__attribute__((address_space(3))) unsigned int*)(ldst),
      16, 0, 0);
}

// fast activations: v_exp_f32 + v_rcp_f32, ~5 VALU inst each.
// ftanh(+inf)=1, ftanh(-inf)=-1 (exp->inf -> rcp->0; exp->0 -> 1-2).
__device__ __forceinline__ float frcp(float x) { return __builtin_amdgcn_rcpf(x); }
__device__ __forceinline__ float ftanh(float x) {
  return 1.0f - 2.0f * frcp(1.0f + __expf(2.0f * x));
}
__device__ __forceinline__ float fsigm(float x) {
  return frcp(1.0f + __expf(-x));
}

// ---------------------------------------------------------------------------
// GEMM1: a1[j] = tanh( hx (MxK) * W1[j]^T (512xK) + b1[j] ), bf16 out.
// 128x128 tile, BK=32, 4 waves 2x2 (64x64 each), 16x16x32 bf16 MFMA.
// LDS XOR swizzle (stored_chunk = logical_chunk ^ ((row>>1)&3)) applied at the
// staging SOURCE column so global_load_lds's lane-linear LDS dest is honored.
// Epilogue bounces through padded LDS (stride 72 el) for 16B coalesced stores.
// ---------------------------------------------------------------------------
__global__ __launch_bounds__(256) void gemm1_kernel(
    const __bf16* __restrict__ A,     // hx bf16 [M][512]
    const __bf16* __restrict__ W,     // [3][512][512] (N,K) row-major
    const float* __restrict__ bias,   // [7][512] fp32, use k=2j+1
    __bf16* __restrict__ out)         // [3][M][512]
{
  const int j = blockIdx.z;
  const int mbase = blockIdx.x * 128;
  const int nbase = blockIdx.y * 128;
  const __bf16* Wj = W + (size_t)j * K * K;

  __shared__ __align__(16) __bf16 smem[8192];
  __bf16* As = smem;          // [128][32]
  __bf16* Bs = smem + 4096;   // [128][32]

  const int tid  = threadIdx.x;
  const int wid  = tid >> 6;
  const int lane = tid & 63;
  const int wm   = (wid >> 1) * 64;
  const int wn   = (wid & 1) * 64;
  const int srow = wid * 16 + (lane >> 2);
  const int scol = ((lane & 3) ^ ((lane >> 3) & 3)) * 8;  // swizzled src chunk
  const int fr   = lane & 15;
  const int kc   = lane >> 4;          // logical k-chunk
  const int sw   = (fr >> 1) & 3;      // row-derived swizzle for frag reads
  const int rowq = kc * 4;

  f32x4 acc[4][4] = {};

  for (int k0 = 0; k0 < K; k0 += BK) {
    __syncthreads();
#pragma unroll
    for (int r = 0; r < 2; ++r) {
      async_copy16(A  + (size_t)(mbase + r * 64 + srow) * K + (k0 + scol),
                   (void*)&As[(r * 64 + wid * 16) * BK]);
      async_copy16(Wj + (size_t)(nbase + r * 64 + srow) * K + (k0 + scol),
                   (void*)&Bs[(r * 64 + wid * 16) * BK]);
    }
    __syncthreads();

    bf16x8 af[4], bfr[4];
#pragma unroll
    for (int i = 0; i < 4; ++i) {
      af[i]  = *(const bf16x8*)&As[(wm + i * 16 + fr) * BK + ((kc ^ sw) * 8)];
      bfr[i] = *(const bf16x8*)&Bs[(wn + i * 16 + fr) * BK + ((kc ^ sw) * 8)];
    }
#pragma unroll
    for (int mi = 0; mi < 4; ++mi)
#pragma unroll
      for (int ni = 0; ni < 4; ++ni)
        acc[mi][ni] = __builtin_amdgcn_mfma_f32_16x16x32_bf16(
            af[mi], bfr[ni], acc[mi][ni], 0, 0, 0);
  }

  // Epilogue: C/D layout col=fr, row=rowq+r. Bounce via LDS for coalescing.
  float bv[4];
  const float* bj = bias + (2 * j + 1) * 512 + nbase + wn;
#pragma unroll
  for (int ni = 0; ni < 4; ++ni) bv[ni] = bj[ni * 16 + fr];

  __bf16* scratch = smem + wid * 1152;  // 16 rows x stride 72 el (144 B)
#pragma unroll 1
  for (int mi = 0; mi < 4; ++mi) {
    __syncthreads();  // protects K-loop LDS reads (mi=0) / prev read phase
#pragma unroll
    for (int ni = 0; ni < 4; ++ni)
#pragma unroll
      for (int r = 0; r < 4; ++r)
        scratch[(rowq + r) * 72 + ni * 16 + fr] =
            (__bf16)ftanh(acc[mi][ni][r] + bv[ni]);
    __syncthreads();
#pragma unroll
    for (int it = 0; it < 2; ++it) {
      const int s = it * 64 + lane;
      const int row = s >> 3, ch = s & 7;
      bf16x8 v = *(const bf16x8*)&scratch[row * 72 + ch * 8];
      const int grow = mbase + wm + mi * 16 + row;
      const int gcol = nbase + wn + ch * 8;
      *(bf16x8*)&out[(size_t)j * M * 512 + (size_t)grow * 512 + gcol] = v;
    }
  }
}

// ---------------------------------------------------------------------------
// GEMM2 fused: per (m,n) tile run nets in order {z(j=2), i2(j=0), f2(j=1)};
// z and partial=i2*z held in registers (bf16x4 x16); f2 pass writes
// out = f2*cx2 + partial as fp32 (full-sector coalescing). No gates buffer.
// ---------------------------------------------------------------------------
__global__ __launch_bounds__(256) void gemm2_kernel(
    const __bf16* __restrict__ A,     // a1 [3][M][512]
    const __bf16* __restrict__ W,     // [3][512][512]
    const float* __restrict__ bias,   // [7][512], use k=2j+1
    const float* __restrict__ cx2,    // [M][512] fp32
    float* __restrict__ out)          // [M][512] fp32
{
  const int mbase = blockIdx.x * 128;
  const int nbase = blockIdx.y * 128;

  __shared__ __align__(16) __bf16 smem[8192];
  __bf16* As = smem;
  __bf16* Bs = smem + 4096;

  const int tid  = threadIdx.x;
  const int wid  = tid >> 6;
  const int lane = tid & 63;
  const int wm   = (wid >> 1) * 64;
  const int wn   = (wid & 1) * 64;
  const int srow = wid * 16 + (lane >> 2);
  const int scol = ((lane & 3) ^ ((lane >> 3) & 3)) * 8;
  const int fr   = lane & 15;
  const int kc   = lane >> 4;
  const int sw   = (fr >> 1) & 3;
  const int rowq = kc * 4;

  bf16x4 held[16];

#pragma unroll 1
  for (int jj = 0; jj < 3; ++jj) {
    const int j = (jj == 0) ? 2 : (jj == 1) ? 0 : 1;  // z, i2, f2
    const __bf16* Aj = A + (size_t)j * M * K;
    const __bf16* Wj = W + (size_t)j * K * K;

    f32x4 acc[4][4] = {};

    for (int k0 = 0; k0 < K; k0 += BK) {
      __syncthreads();
#pragma unroll
      for (int r = 0; r < 2; ++r) {
        async_copy16(Aj + (size_t)(mbase + r * 64 + srow) * K + (k0 + scol),
                     (void*)&As[(r * 64 + wid * 16) * BK]);
        async_copy16(Wj + (size_t)(nbase + r * 64 + srow) * K + (k0 + scol),
                     (void*)&Bs[(r * 64 + wid * 16) * BK]);
      }
      __syncthreads();

      bf16x8 af[4], bfr[4];
#pragma unroll
      for (int i = 0; i < 4; ++i) {
        af[i]  = *(const bf16x8*)&As[(wm + i * 16 + fr) * BK + ((kc ^ sw) * 8)];
        bfr[i] = *(const bf16x8*)&Bs[(wn + i * 16 + fr) * BK + ((kc ^ sw) * 8)];
      }
#pragma unroll
      for (int mi = 0; mi < 4; ++mi)
#pragma unroll
        for (int ni = 0; ni < 4; ++ni)
          acc[mi][ni] = __builtin_amdgcn_mfma_f32_16x16x32_bf16(
              af[mi], bfr[ni], acc[mi][ni], 0, 0, 0);
    }

    float bv[4];
    const float* bj = bias + (2 * j + 1) * 512 + nbase + wn;
#pragma unroll
    for (int ni = 0; ni < 4; ++ni) bv[ni] = bj[ni * 16 + fr];

    if (jj == 0) {
      // z = tanh(sigmoid(tanh(h2)))
#pragma unroll
      for (int mi = 0; mi < 4; ++mi)
#pragma unroll
        for (int ni = 0; ni < 4; ++ni) {
          bf16x4 h;
#pragma unroll
          for (int r = 0; r < 4; ++r)
            h[r] = (__bf16)ftanh(fsigm(ftanh(acc[mi][ni][r] + bv[ni])));
          held[mi * 4 + ni] = h;
        }
    } else if (jj == 1) {
      // partial = i2 * z
#pragma unroll
      for (int mi = 0; mi < 4; ++mi)
#pragma unroll
        for (int ni = 0; ni < 4; ++ni) {
          f32x4 z = __builtin_convertvector(held[mi * 4 + ni], f32x4);
          bf16x4 h;
#pragma unroll
          for (int r = 0; r < 4; ++r)
            h[r] = (__bf16)(fsigm(ftanh(acc[mi][ni][r] + bv[ni])) * z[r]);
          held[mi * 4 + ni] = h;
        }
    } else {
      // out = f2*cx2 + partial  (fp32: 16 lanes x 4B = full 64B sectors)
#pragma unroll
      for (int mi = 0; mi < 4; ++mi)
#pragma unroll
        for (int ni = 0; ni < 4; ++ni) {
          f32x4 p = __builtin_convertvector(held[mi * 4 + ni], f32x4);
          const int col = nbase + wn + ni * 16 + fr;
#pragma unroll
          for (int r = 0; r < 4; ++r) {
            const int row = mbase + wm + mi * 16 + rowq + r;
            float f2 = fsigm(ftanh(acc[mi][ni][r] + bv[ni]));
            out[(size_t)row * 512 + col] =
                f2 * cx2[(size_t)row * 512 + col] + p[r];
          }
        }
    }
  }
}

__global__ __launch_bounds__(256) void cvt_hx(const float* __restrict__ src,
                                              __bf16* __restrict__ dst) {
  const size_t i = ((size_t)blockIdx.x * 256 + threadIdx.x) * 4;
  f32x4 v = *(const f32x4*)&src[i];
  *(bf16x4*)&dst[i] = __builtin_convertvector(v, bf16x4);
}

// pick k = 2j+1 from [7][512][512] -> [3][512][512] bf16
__global__ __launch_bounds__(256) void cvt_w(const float* __restrict__ src,
                                             __bf16* __restrict__ dst) {
  const int j = blockIdx.y;
  const size_t i = ((size_t)blockIdx.x * 256 + threadIdx.x) * 4;
  f32x4 v = *(const f32x4*)&src[(size_t)(2 * j + 1) * 262144 + i];
  *(bf16x4*)&dst[(size_t)j * 262144 + i] = __builtin_convertvector(v, bf16x4);
}

extern "C" void kernel_launch(void* const* d_in, const int* in_sizes, int n_in,
                              void* d_out, int out_size, void* d_ws, size_t ws_size,
                              hipStream_t stream) {
  const float* hx  = (const float*)d_in[0];
  // d_in[1] = cx1 (dead: cy1 is never returned)
  const float* cx2 = (const float*)d_in[2];
  const float* W1  = (const float*)d_in[3];
  const float* b1  = (const float*)d_in[4];
  const float* W2  = (const float*)d_in[5];
  const float* b2  = (const float*)d_in[6];
  float* out = (float*)d_out;

  char* ws = (char*)d_ws;
  // hxb @0 (16 MB) | W1b @16777216 (1.5 MB) | W2b @18350080 (1.5 MB)
  // a1  @19922944 (50 MB)  -> total ~70 MB
  __bf16* hxb = (__bf16*)(ws);
  __bf16* W1b = (__bf16*)(ws + 16777216);
  __bf16* W2b = (__bf16*)(ws + 18350080);
  __bf16* a1  = (__bf16*)(ws + 19922944);

  cvt_hx<<<8192, 256, 0, stream>>>(hx, hxb);
  cvt_w<<<dim3(256, 3), 256, 0, stream>>>(W1, W1b);
  cvt_w<<<dim3(256, 3), 256, 0, stream>>>(W2, W2b);

  gemm1_kernel<<<dim3(128, 4, 3), 256, 0, stream>>>(hxb, W1b, b1, a1);
  gemm2_kernel<<<dim3(128, 4), 256, 0, stream>>>(a1, W2b, b2, cx2, out);
}

// Round 3
// 271.926 us; speedup vs baseline: 2.7193x; 2.7193x over previous
//
#include <hip/hip_runtime.h>
#include <hip/hip_bf16.h>

typedef __attribute__((ext_vector_type(8))) __bf16 bf16x8;
typedef __attribute__((ext_vector_type(4))) __bf16 bf16x4;
typedef __attribute__((ext_vector_type(4))) float f32x4;

constexpr int M = 16384;
constexpr int K = 512;
constexpr int BK = 32;

__device__ __forceinline__ void async_copy16(const void* gsrc, void* ldst) {
  __builtin_amdgcn_global_load_lds(
      (const __attribute__((address_space(1))) unsigned int*)(gsrc),
      (__attribute__((address_space(3))) unsigned int*)(ldst),
      16, 0, 0);
}

// fast activations: v_exp_f32 + v_rcp_f32, ~5 VALU inst each.
// ftanh(+inf)=1, ftanh(-inf)=-1 (exp->inf -> rcp->0; exp->0 -> 1-2).
__device__ __forceinline__ float frcp(float x) { return __builtin_amdgcn_rcpf(x); }
__device__ __forceinline__ float ftanh(float x) {
  return 1.0f - 2.0f * frcp(1.0f + __expf(2.0f * x));
}
__device__ __forceinline__ float fsigm(float x) {
  return frcp(1.0f + __expf(-x));
}

// ---------------------------------------------------------------------------
// GEMM1: a1[j] = tanh( hx (MxK) * W1[j]^T (512xK) + b1[j] ), bf16 out.
// 128x128 tile, BK=32, 4 waves 2x2 (64x64 each), 16x16x32 bf16 MFMA.
// LDS XOR swizzle applied at the staging SOURCE column so global_load_lds's
// lane-linear LDS dest is honored. Epilogue bounces through padded LDS
// (stride 72 el) for 16B coalesced stores.
// NOTE: epilogue mi-loop MUST be fully unrolled — `#pragma unroll 1` made
// acc[] dynamically indexed -> scratch spill -> 1.7 GB scratch traffic (R2).
// ---------------------------------------------------------------------------
__global__ __launch_bounds__(256) void gemm1_kernel(
    const __bf16* __restrict__ A,     // hx bf16 [M][512]
    const __bf16* __restrict__ W,     // [3][512][512] (N,K) row-major
    const float* __restrict__ bias,   // [7][512] fp32, use k=2j+1
    __bf16* __restrict__ out)         // [3][M][512]
{
  const int j = blockIdx.z;
  const int mbase = blockIdx.x * 128;
  const int nbase = blockIdx.y * 128;
  const __bf16* Wj = W + (size_t)j * K * K;

  __shared__ __align__(16) __bf16 smem[8192];
  __bf16* As = smem;          // [128][32]
  __bf16* Bs = smem + 4096;   // [128][32]

  const int tid  = threadIdx.x;
  const int wid  = tid >> 6;
  const int lane = tid & 63;
  const int wm   = (wid >> 1) * 64;
  const int wn   = (wid & 1) * 64;
  const int srow = wid * 16 + (lane >> 2);
  const int scol = ((lane & 3) ^ ((lane >> 3) & 3)) * 8;  // swizzled src chunk
  const int fr   = lane & 15;
  const int kc   = lane >> 4;          // logical k-chunk
  const int sw   = (fr >> 1) & 3;      // row-derived swizzle for frag reads
  const int rowq = kc * 4;

  f32x4 acc[4][4] = {};

  for (int k0 = 0; k0 < K; k0 += BK) {
    __syncthreads();
#pragma unroll
    for (int r = 0; r < 2; ++r) {
      async_copy16(A  + (size_t)(mbase + r * 64 + srow) * K + (k0 + scol),
                   (void*)&As[(r * 64 + wid * 16) * BK]);
      async_copy16(Wj + (size_t)(nbase + r * 64 + srow) * K + (k0 + scol),
                   (void*)&Bs[(r * 64 + wid * 16) * BK]);
    }
    __syncthreads();

    bf16x8 af[4], bfr[4];
#pragma unroll
    for (int i = 0; i < 4; ++i) {
      af[i]  = *(const bf16x8*)&As[(wm + i * 16 + fr) * BK + ((kc ^ sw) * 8)];
      bfr[i] = *(const bf16x8*)&Bs[(wn + i * 16 + fr) * BK + ((kc ^ sw) * 8)];
    }
#pragma unroll
    for (int mi = 0; mi < 4; ++mi)
#pragma unroll
      for (int ni = 0; ni < 4; ++ni)
        acc[mi][ni] = __builtin_amdgcn_mfma_f32_16x16x32_bf16(
            af[mi], bfr[ni], acc[mi][ni], 0, 0, 0);
  }

  // Epilogue: C/D layout col=fr, row=rowq+r. Bounce via LDS for coalescing.
  float bv[4];
  const float* bj = bias + (2 * j + 1) * 512 + nbase + wn;
#pragma unroll
  for (int ni = 0; ni < 4; ++ni) bv[ni] = bj[ni * 16 + fr];

  __bf16* scratch = smem + wid * 1152;  // 16 rows x stride 72 el (144 B)
#pragma unroll
  for (int mi = 0; mi < 4; ++mi) {
    __syncthreads();  // protects K-loop LDS reads (mi=0) / prev read phase
#pragma unroll
    for (int ni = 0; ni < 4; ++ni)
#pragma unroll
      for (int r = 0; r < 4; ++r)
        scratch[(rowq + r) * 72 + ni * 16 + fr] =
            (__bf16)ftanh(acc[mi][ni][r] + bv[ni]);
    __syncthreads();
#pragma unroll
    for (int it = 0; it < 2; ++it) {
      const int s = it * 64 + lane;
      const int row = s >> 3, ch = s & 7;
      bf16x8 v = *(const bf16x8*)&scratch[row * 72 + ch * 8];
      const int grow = mbase + wm + mi * 16 + row;
      const int gcol = nbase + wn + ch * 8;
      *(bf16x8*)&out[(size_t)j * M * 512 + (size_t)grow * 512 + gcol] = v;
    }
  }
}

// ---------------------------------------------------------------------------
// GEMM2 fused: per (m,n) tile run nets in order {z(j=2), i2(j=0), f2(j=1)};
// z and partial=i2*z held in registers (bf16x4 x16); f2 pass writes
// out = f2*cx2 + partial as fp32 (full-sector coalescing). No gates buffer.
// acc/held indices are all compile-time constants within each jj iteration,
// so `#pragma unroll 1` on jj is safe (verified: no spill in R2).
// ---------------------------------------------------------------------------
__global__ __launch_bounds__(256) void gemm2_kernel(
    const __bf16* __restrict__ A,     // a1 [3][M][512]
    const __bf16* __restrict__ W,     // [3][512][512]
    const float* __restrict__ bias,   // [7][512], use k=2j+1
    const float* __restrict__ cx2,    // [M][512] fp32
    float* __restrict__ out)          // [M][512] fp32
{
  const int mbase = blockIdx.x * 128;
  const int nbase = blockIdx.y * 128;

  __shared__ __align__(16) __bf16 smem[8192];
  __bf16* As = smem;
  __bf16* Bs = smem + 4096;

  const int tid  = threadIdx.x;
  const int wid  = tid >> 6;
  const int lane = tid & 63;
  const int wm   = (wid >> 1) * 64;
  const int wn   = (wid & 1) * 64;
  const int srow = wid * 16 + (lane >> 2);
  const int scol = ((lane & 3) ^ ((lane >> 3) & 3)) * 8;
  const int fr   = lane & 15;
  const int kc   = lane >> 4;
  const int sw   = (fr >> 1) & 3;
  const int rowq = kc * 4;

  bf16x4 held[16];

#pragma unroll 1
  for (int jj = 0; jj < 3; ++jj) {
    const int j = (jj == 0) ? 2 : (jj == 1) ? 0 : 1;  // z, i2, f2
    const __bf16* Aj = A + (size_t)j * M * K;
    const __bf16* Wj = W + (size_t)j * K * K;

    f32x4 acc[4][4] = {};

    for (int k0 = 0; k0 < K; k0 += BK) {
      __syncthreads();
#pragma unroll
      for (int r = 0; r < 2; ++r) {
        async_copy16(Aj + (size_t)(mbase + r * 64 + srow) * K + (k0 + scol),
                     (void*)&As[(r * 64 + wid * 16) * BK]);
        async_copy16(Wj + (size_t)(nbase + r * 64 + srow) * K + (k0 + scol),
                     (void*)&Bs[(r * 64 + wid * 16) * BK]);
      }
      __syncthreads();

      bf16x8 af[4], bfr[4];
#pragma unroll
      for (int i = 0; i < 4; ++i) {
        af[i]  = *(const bf16x8*)&As[(wm + i * 16 + fr) * BK + ((kc ^ sw) * 8)];
        bfr[i] = *(const bf16x8*)&Bs[(wn + i * 16 + fr) * BK + ((kc ^ sw) * 8)];
      }
#pragma unroll
      for (int mi = 0; mi < 4; ++mi)
#pragma unroll
        for (int ni = 0; ni < 4; ++ni)
          acc[mi][ni] = __builtin_amdgcn_mfma_f32_16x16x32_bf16(
              af[mi], bfr[ni], acc[mi][ni], 0, 0, 0);
    }

    float bv[4];
    const float* bj = bias + (2 * j + 1) * 512 + nbase + wn;
#pragma unroll
    for (int ni = 0; ni < 4; ++ni) bv[ni] = bj[ni * 16 + fr];

    if (jj == 0) {
      // z = tanh(sigmoid(tanh(h2)))
#pragma unroll
      for (int mi = 0; mi < 4; ++mi)
#pragma unroll
        for (int ni = 0; ni < 4; ++ni) {
          bf16x4 h;
#pragma unroll
          for (int r = 0; r < 4; ++r)
            h[r] = (__bf16)ftanh(fsigm(ftanh(acc[mi][ni][r] + bv[ni])));
          held[mi * 4 + ni] = h;
        }
    } else if (jj == 1) {
      // partial = i2 * z
#pragma unroll
      for (int mi = 0; mi < 4; ++mi)
#pragma unroll
        for (int ni = 0; ni < 4; ++ni) {
          f32x4 z = __builtin_convertvector(held[mi * 4 + ni], f32x4);
          bf16x4 h;
#pragma unroll
          for (int r = 0; r < 4; ++r)
            h[r] = (__bf16)(fsigm(ftanh(acc[mi][ni][r] + bv[ni])) * z[r]);
          held[mi * 4 + ni] = h;
        }
    } else {
      // out = f2*cx2 + partial  (fp32: 16 lanes x 4B = full 64B sectors)
#pragma unroll
      for (int mi = 0; mi < 4; ++mi)
#pragma unroll
        for (int ni = 0; ni < 4; ++ni) {
          f32x4 p = __builtin_convertvector(held[mi * 4 + ni], f32x4);
          const int col = nbase + wn + ni * 16 + fr;
#pragma unroll
          for (int r = 0; r < 4; ++r) {
            const int row = mbase + wm + mi * 16 + rowq + r;
            float f2 = fsigm(ftanh(acc[mi][ni][r] + bv[ni]));
            out[(size_t)row * 512 + col] =
                f2 * cx2[(size_t)row * 512 + col] + p[r];
          }
        }
    }
  }
}

__global__ __launch_bounds__(256) void cvt_hx(const float* __restrict__ src,
                                              __bf16* __restrict__ dst) {
  const size_t i = ((size_t)blockIdx.x * 256 + threadIdx.x) * 4;
  f32x4 v = *(const f32x4*)&src[i];
  *(bf16x4*)&dst[i] = __builtin_convertvector(v, bf16x4);
}

// pick k = 2j+1 from [7][512][512] -> [3][512][512] bf16
__global__ __launch_bounds__(256) void cvt_w(const float* __restrict__ src,
                                             __bf16* __restrict__ dst) {
  const int j = blockIdx.y;
  const size_t i = ((size_t)blockIdx.x * 256 + threadIdx.x) * 4;
  f32x4 v = *(const f32x4*)&src[(size_t)(2 * j + 1) * 262144 + i];
  *(bf16x4*)&dst[(size_t)j * 262144 + i] = __builtin_convertvector(v, bf16x4);
}

extern "C" void kernel_launch(void* const* d_in, const int* in_sizes, int n_in,
                              void* d_out, int out_size, void* d_ws, size_t ws_size,
                              hipStream_t stream) {
  const float* hx  = (const float*)d_in[0];
  // d_in[1] = cx1 (dead: cy1 is never returned)
  const float* cx2 = (const float*)d_in[2];
  const float* W1  = (const float*)d_in[3];
  const float* b1  = (const float*)d_in[4];
  const float* W2  = (const float*)d_in[5];
  const float* b2  = (const float*)d_in[6];
  float* out = (float*)d_out;

  char* ws = (char*)d_ws;
  // hxb @0 (16 MB) | W1b @16777216 (1.5 MB) | W2b @18350080 (1.5 MB)
  // a1  @19922944 (50 MB)  -> total ~70 MB
  __bf16* hxb = (__bf16*)(ws);
  __bf16* W1b = (__bf16*)(ws + 16777216);
  __bf16* W2b = (__bf16*)(ws + 18350080);
  __bf16* a1  = (__bf16*)(ws + 19922944);

  cvt_hx<<<8192, 256, 0, stream>>>(hx, hxb);
  cvt_w<<<dim3(256, 3), 256, 0, stream>>>(W1, W1b);
  cvt_w<<<dim3(256, 3), 256, 0, stream>>>(W2, W2b);

  gemm1_kernel<<<dim3(128, 4, 3), 256, 0, stream>>>(hxb, W1b, b1, a1);
  gemm2_kernel<<<dim3(128, 4), 256, 0, stream>>>(a1, W2b, b2, cx2, out);
}

// Round 4
// 233.962 us; speedup vs baseline: 3.1606x; 1.1623x over previous
//
#include <hip/hip_runtime.h>
#include <hip/hip_bf16.h>

typedef __attribute__((ext_vector_type(8))) __bf16 bf16x8;
typedef __attribute__((ext_vector_type(4))) __bf16 bf16x4;
typedef __attribute__((ext_vector_type(4))) float f32x4;

constexpr int M = 16384;
constexpr int K = 512;
constexpr int BK = 32;

__device__ __forceinline__ void async_copy16(const void* gsrc, void* ldst) {
  __builtin_amdgcn_global_load_lds(
      (const __attribute__((address_space(1))) unsigned int*)(gsrc),
      (__attribute__((address_space(3))) unsigned int*)(ldst),
      16, 0, 0);
}

// fast activations: v_exp_f32 + v_rcp_f32. Correct saturation at +/-inf.
__device__ __forceinline__ float frcp(float x) { return __builtin_amdgcn_rcpf(x); }
__device__ __forceinline__ float ftanh(float x) {
  return 1.0f - 2.0f * frcp(1.0f + __expf(2.0f * x));
}
__device__ __forceinline__ float fsigm(float x) {
  return frcp(1.0f + __expf(-x));
}

// ---------------------------------------------------------------------------
// GEMM: out[j] = act( A[j] (MxK) * W[j]^T (512xK) + b[j] ), bf16 out.
// 128x128 tile, BK=32, 4 waves 2x2 (64x64 each), 16x16x32 bf16 MFMA.
// Pipelined ping-pong LDS: stage(k+1) issued AFTER the barrier, so each
// barrier drains loads issued one full MFMA-phase earlier (R3 was
// latency-bound: stage -> immediate barrier exposed full load latency,
// MfmaUtil 9%). XOR swizzle on the staging SOURCE column keeps
// global_load_lds's lane-linear LDS dest valid; frag reads un-swizzle.
// Epilogue: whole-tile padded LDS scratch ([128][136]) -> one barrier pair,
// 8x bf16x8 fully-coalesced global stores.
// LAYER1 act: tanh. LAYER2: sigmoid(tanh(.)); net j==2 (z): tanh(sigmoid(tanh)).
// NOTE: never partially-unroll loops indexing acc[] (R2: scratch spill).
// ---------------------------------------------------------------------------
template <int LAYER>
__global__ __launch_bounds__(256) void gemm_kernel(
    const __bf16* __restrict__ A,     // LAYER1: hx [M][512]; LAYER2: a1 [3][M][512]
    const __bf16* __restrict__ W,     // [3][512][512] (N,K) row-major
    const float* __restrict__ bias,   // [7][512] fp32, use k=2j+1
    __bf16* __restrict__ out)         // [3][M][512] bf16
{
  const int j = blockIdx.z;
  const int mbase = blockIdx.x * 128;
  const int nbase = blockIdx.y * 128;
  const __bf16* Aj = (LAYER == 2) ? (A + (size_t)j * M * K) : A;
  const __bf16* Wj = W + (size_t)j * K * K;

  // dbuf: 2 x (As 4096 el + Bs 4096 el) = 16384 el (32 KB).
  // epilogue scratch: 128 rows x stride 136 el = 17400 el (34 KB).
  __shared__ __align__(16) __bf16 smem[17408];

  const int tid  = threadIdx.x;
  const int wid  = tid >> 6;
  const int lane = tid & 63;
  const int wm   = (wid >> 1) * 64;
  const int wn   = (wid & 1) * 64;
  const int srow = wid * 16 + (lane >> 2);
  const int scol = ((lane & 3) ^ ((lane >> 3) & 3)) * 8;  // swizzled src chunk
  const int fr   = lane & 15;
  const int kc   = lane >> 4;
  const int sw   = (fr >> 1) & 3;
  const int rowq = kc * 4;

  auto stage = [&](int p, int k0) {
    __bf16* As = smem + p * 8192;
    __bf16* Bs = As + 4096;
#pragma unroll
    for (int r = 0; r < 2; ++r) {
      async_copy16(Aj + (size_t)(mbase + r * 64 + srow) * K + (k0 + scol),
                   (void*)&As[(r * 64 + wid * 16) * BK]);
      async_copy16(Wj + (size_t)(nbase + r * 64 + srow) * K + (k0 + scol),
                   (void*)&Bs[(r * 64 + wid * 16) * BK]);
    }
  };

  f32x4 acc[4][4] = {};

  stage(0, 0);
  int p = 0;
  for (int k0 = 0; k0 < K; k0 += BK) {
    __syncthreads();  // drains stage(p) issued last iter (or prologue)
    if (k0 + BK < K) stage(p ^ 1, k0 + BK);  // in flight during MFMA below

    const __bf16* As = smem + p * 8192;
    const __bf16* Bs = As + 4096;
    bf16x8 af[4], bfr[4];
#pragma unroll
    for (int i = 0; i < 4; ++i) {
      af[i]  = *(const bf16x8*)&As[(wm + i * 16 + fr) * BK + ((kc ^ sw) * 8)];
      bfr[i] = *(const bf16x8*)&Bs[(wn + i * 16 + fr) * BK + ((kc ^ sw) * 8)];
    }
#pragma unroll
    for (int mi = 0; mi < 4; ++mi)
#pragma unroll
      for (int ni = 0; ni < 4; ++ni)
        acc[mi][ni] = __builtin_amdgcn_mfma_f32_16x16x32_bf16(
            af[mi], bfr[ni], acc[mi][ni], 0, 0, 0);
    p ^= 1;
  }

  // Epilogue. C/D layout: col=fr, row=rowq+r.
  float bv[4];
  const float* bj = bias + (2 * j + 1) * 512 + nbase + wn;
#pragma unroll
  for (int ni = 0; ni < 4; ++ni) bv[ni] = bj[ni * 16 + fr];

  __syncthreads();  // all frag reads done; smem reusable as C scratch
#pragma unroll
  for (int mi = 0; mi < 4; ++mi)
#pragma unroll
    for (int ni = 0; ni < 4; ++ni)
#pragma unroll
      for (int r = 0; r < 4; ++r) {
        float v = acc[mi][ni][r] + bv[ni];
        float res;
        if constexpr (LAYER == 1) {
          res = ftanh(v);
        } else {
          res = (j == 2) ? ftanh(fsigm(ftanh(v))) : fsigm(ftanh(v));
        }
        smem[(wm + mi * 16 + rowq + r) * 136 + (wn + ni * 16 + fr)] =
            (__bf16)res;
      }
  __syncthreads();
#pragma unroll
  for (int it = 0; it < 8; ++it) {
    const int s = it * 256 + tid;   // 0..2047
    const int row = s >> 4, ch = s & 15;
    bf16x8 v = *(const bf16x8*)&smem[row * 136 + ch * 8];
    *(bf16x8*)&out[(size_t)j * M * 512 + (size_t)(mbase + row) * 512 +
                   (nbase + ch * 8)] = v;
  }
}

// cy2 = f2*cx2 + i2*z    gates = [i2 | f2 | z] bf16 [3][M][512]
__global__ __launch_bounds__(256) void final_kernel(
    const __bf16* __restrict__ gates, const float* __restrict__ cx2,
    float* __restrict__ out)
{
  constexpr size_t NH = (size_t)M * 512;
  const size_t i = ((size_t)blockIdx.x * 256 + threadIdx.x) * 8;
  bf16x8 i2 = *(const bf16x8*)&gates[i];
  bf16x8 f2 = *(const bf16x8*)&gates[NH + i];
  bf16x8 zz = *(const bf16x8*)&gates[2 * NH + i];
  f32x4 c0 = *(const f32x4*)&cx2[i];
  f32x4 c1 = *(const f32x4*)&cx2[i + 4];
#pragma unroll
  for (int h = 0; h < 2; ++h) {
    f32x4 r;
#pragma unroll
    for (int q = 0; q < 4; ++q) {
      const int e = h * 4 + q;
      r[q] = (float)f2[e] * (h ? c1[q] : c0[q]) + (float)i2[e] * (float)zz[e];
    }
    *(f32x4*)&out[i + h * 4] = r;
  }
}

__global__ __launch_bounds__(256) void cvt_hx(const float* __restrict__ src,
                                              __bf16* __restrict__ dst) {
  const size_t i = ((size_t)blockIdx.x * 256 + threadIdx.x) * 4;
  f32x4 v = *(const f32x4*)&src[i];
  *(bf16x4*)&dst[i] = __builtin_convertvector(v, bf16x4);
}

// pick k = 2j+1 from [7][512][512] -> [3][512][512] bf16
__global__ __launch_bounds__(256) void cvt_w(const float* __restrict__ src,
                                             __bf16* __restrict__ dst) {
  const int j = blockIdx.y;
  const size_t i = ((size_t)blockIdx.x * 256 + threadIdx.x) * 4;
  f32x4 v = *(const f32x4*)&src[(size_t)(2 * j + 1) * 262144 + i];
  *(bf16x4*)&dst[(size_t)j * 262144 + i] = __builtin_convertvector(v, bf16x4);
}

extern "C" void kernel_launch(void* const* d_in, const int* in_sizes, int n_in,
                              void* d_out, int out_size, void* d_ws, size_t ws_size,
                              hipStream_t stream) {
  const float* hx  = (const float*)d_in[0];
  // d_in[1] = cx1 (dead: cy1 is never returned)
  const float* cx2 = (const float*)d_in[2];
  const float* W1  = (const float*)d_in[3];
  const float* b1  = (const float*)d_in[4];
  const float* W2  = (const float*)d_in[5];
  const float* b2  = (const float*)d_in[6];
  float* out = (float*)d_out;

  char* ws = (char*)d_ws;
  // hxb @0 (16 MB) | W1b @16777216 | W2b @18350080 | a1 @19922944 (50 MB)
  // gates @70254592 (50 MB) -> total ~121 MB
  __bf16* hxb   = (__bf16*)(ws);
  __bf16* W1b   = (__bf16*)(ws + 16777216);
  __bf16* W2b   = (__bf16*)(ws + 18350080);
  __bf16* a1    = (__bf16*)(ws + 19922944);
  __bf16* gates = (__bf16*)(ws + 70254592);

  cvt_hx<<<8192, 256, 0, stream>>>(hx, hxb);
  cvt_w<<<dim3(256, 3), 256, 0, stream>>>(W1, W1b);
  cvt_w<<<dim3(256, 3), 256, 0, stream>>>(W2, W2b);

  gemm_kernel<1><<<dim3(128, 4, 3), 256, 0, stream>>>(hxb, W1b, b1, a1);
  gemm_kernel<2><<<dim3(128, 4, 3), 256, 0, stream>>>(a1, W2b, b2, gates);

  final_kernel<<<4096, 256, 0, stream>>>(gates, cx2, out);
}